// Round 8
// baseline (389.036 us; speedup 1.0000x reference)
//
#include <hip/hip_runtime.h>
#include <hip/hip_cooperative_groups.h>

namespace cg = cooperative_groups;

#define B_ 32
#define T_ 2048
#define H_ 256
#define L_ 2049   // T_ + 1

// ---------------- helpers ----------------
__device__ inline double waveReduceD(double v) {
#pragma unroll
  for (int off = 32; off > 0; off >>= 1) v += __shfl_xor(v, off, 64);
  return v;
}

typedef float vfloat4 __attribute__((ext_vector_type(4)));
__device__ inline void nt_store4(float4 v, float* p) {
  vfloat4 t;
  t.x = v.x; t.y = v.y; t.z = v.z; t.w = v.w;
  __builtin_nontemporal_store(t, (vfloat4*)p);
}

// ================= fused cooperative kernel =================
// 512 blocks x 256 threads, 2 blocks/CU guaranteed by __launch_bounds__.
// P0: fold W1/W2 -> vd,c0 (blocks 0..15)
// P1: row dots d1,d2,absS (all blocks, 128 rows each)
// P2: weights + exact closed-form fire solve (blocks 0..31, one per b)
// P3: all cif rows, grid-stride over (b,pos) (all blocks)
__global__ void __launch_bounds__(256, 2) cif_fused(
    const float* __restrict__ x, const float* __restrict__ mask,
    const float* __restrict__ W1, const float* __restrict__ b1,
    const float* __restrict__ W2, const float* __restrict__ b2,
    const int* __restrict__ is_tr,
    double* __restrict__ vd, double* __restrict__ c0p,
    double* __restrict__ d1, double* __restrict__ d2,
    float* __restrict__ absS, float* __restrict__ wsc,
    int* __restrict__ fireT, int* __restrict__ nAllArr, int* __restrict__ nUnmArr,
    float* __restrict__ o_cif, float* __restrict__ o_ori,
    float* __restrict__ o_ff, float* __restrict__ o_np, float* __restrict__ o_sa) {
  cg::grid_group grid = cg::this_grid();
  __shared__ double s_P[T_];        // 16 KB (P0 scratch / P2 prefix sums)
  __shared__ double s_tot[4];
  __shared__ double s_red[4][3];
  __shared__ double s_tot2[4];
  __shared__ double s_mtot[4];
  __shared__ int s_int[2];
  int tid = threadIdx.x;

  // ---------------- P0: fold linear layers (blocks 0..15) ----------------
  if (blockIdx.x < 16) {
    double (*s_p)[32] = (double(*)[32])s_P;     // 8x32 doubles
    double* red = s_P + 256;                    // 256 doubles
    int cl = tid & 31, sl = tid >> 5;
    int c = blockIdx.x * 32 + cl;
    double acc0 = 0.0, acc1 = 0.0;
#pragma unroll 4
    for (int o = sl * 64; o < sl * 64 + 64; o += 2) {
      acc0 += (double)W2[o] * (double)W1[o * 512 + c];
      acc1 += (double)W2[o + 1] * (double)W1[(o + 1) * 512 + c];
    }
    s_p[sl][cl] = acc0 + acc1;
    __syncthreads();
    if (sl == 0) {
      double v = 0.0;
#pragma unroll
      for (int i = 0; i < 8; ++i) v += s_p[i][cl];
      vd[c] = v;
    }
    if (blockIdx.x == 0) {
      __syncthreads();
      red[tid] = (double)W2[tid] * (double)b1[tid] +
                 (double)W2[tid + 256] * (double)b1[tid + 256];
      __syncthreads();
      for (int s = 128; s > 0; s >>= 1) {
        if (tid < s) red[tid] += red[tid + s];
        __syncthreads();
      }
      if (tid == 0) c0p[0] = red[0] + (double)b2[0];
    }
  }
  grid.sync();

  // ---------------- P1: row dots, 16 lanes/row, 128 rows/block ------------
  {
    int s = tid & 15;          // segment within row
    int slot = tid >> 4;       // 16 slots x 4 rows x 2 groups = 128 rows
    double v12[16], v2v[16];
#pragma unroll
    for (int k = 0; k < 16; ++k) {
      double bv = vd[256 + s * 16 + k];
      v2v[k] = bv;
      v12[k] = vd[s * 16 + k] + bv;
    }
#pragma unroll
    for (int g = 0; g < 2; ++g) {
      long rowBase = (long)blockIdx.x * 128 + g * 64;
#pragma unroll
      for (int i = 0; i < 4; ++i) {
        long row = rowBase + slot * 4 + i;
        const float4* xr = (const float4*)(x + row * H_ + s * 16);
        float4 a0 = xr[0], a1 = xr[1], a2 = xr[2], a3 = xr[3];
        float e[16];
        *(float4*)(e + 0) = a0; *(float4*)(e + 4) = a1;
        *(float4*)(e + 8) = a2; *(float4*)(e + 12) = a3;
        double p1 = 0.0, p2 = 0.0;
        bool nz = false;
#pragma unroll
        for (int k = 0; k < 16; ++k) {
          p1 += (double)e[k] * v12[k];
          p2 += (double)e[k] * v2v[k];
          nz |= (e[k] != 0.0f);
        }
        float nzf = nz ? 1.0f : 0.0f;
#pragma unroll
        for (int off = 1; off < 16; off <<= 1) {  // stays in the 16-group
          p1 += __shfl_xor(p1, off, 64);
          p2 += __shfl_xor(p2, off, 64);
          nzf += __shfl_xor(nzf, off, 64);
        }
        if (s == 0) {
          d1[row] = p1;
          d2[row] = p2;
          absS[row] = (nzf > 0.0f) ? 1.0f : 0.0f;
        }
      }
    }
  }
  grid.sync();

  // ---------------- P2: weights + exact fire solve (blocks 0..31) ---------
  // C_t = t + min(1, M_t), M_t = min_{s<=t}(Kp_s - s), Kp = max(0,ceil(S-1)).
  if (blockIdx.x < 32) {
    int b = blockIdx.x;
    int lane = tid & 63, wv = tid >> 6;
    int t0 = tid * 8;
    const double* d1b = d1 + (long)b * T_;
    const double* d2b = d2 + (long)b * T_;
    const float* asb = absS + (long)b * T_;
    double c0 = c0p[0];

    // prefix sum of d2 -> s_P
    double r2[8];
    {
      double run2 = 0.0;
#pragma unroll
      for (int k = 0; k < 8; ++k) { run2 += d2b[t0 + k]; r2[k] = run2; }
      double sc2 = run2;
#pragma unroll
      for (int off = 1; off < 64; off <<= 1) {
        double n = __shfl_up(sc2, off, 64);
        if (lane >= off) sc2 += n;
      }
      if (lane == 63) s_tot[wv] = sc2;
      __syncthreads();
      double base2 = 0.0;
      for (int i = 0; i < wv; ++i) base2 += s_tot[i];
      double e2 = base2 + (sc2 - run2);
#pragma unroll
      for (int k = 0; k < 8; ++k) s_P[t0 + k] = e2 + r2[k];
    }
    __syncthreads();

    // Part A: w = clip(relu(d1 - windowmean + c0), 0, 1)
    double wd[8];
    double sa = 0.0, fpc = 0.0;
#pragma unroll
    for (int k = 0; k < 8; ++k) {
      int t = t0 + k;
      double wvv;
      if (t == 0) {
        wvv = d1b[0] - s_P[0] + c0;  // hist[0] = x[0]
      } else {
        int start = t - 10; if (start < 0) start = 0;
        double ws_ = s_P[t - 1] - (start > 0 ? s_P[start - 1] : 0.0);
        wvv = d1b[t] - ws_ / (double)(t - start) + c0;
      }
      wvv = wvv < 0.0 ? 0.0 : (wvv > 1.0 ? 1.0 : wvv);
      wd[k] = wvv;
      sa += wvv;
      fpc += (asb[t] != 0.0f) ? 1.0 : 0.0;
    }
    {
      float4* ov = (float4*)(o_ori + (long)b * T_ + t0);
      ov[0] = make_float4((float)wd[0], (float)wd[1], (float)wd[2], (float)wd[3]);
      ov[1] = make_float4((float)wd[4], (float)wd[5], (float)wd[6], (float)wd[7]);
    }
    double ms = (tid < 200) ? (double)mask[(long)b * 200 + tid] : 0.0;
    double sar = waveReduceD(sa), fpr = waveReduceD(fpc), msr = waveReduceD(ms);
    if (lane == 0) { s_red[wv][0] = sar; s_red[wv][1] = fpr; s_red[wv][2] = msr; }
    __syncthreads();
    double sumA = s_red[0][0] + s_red[1][0] + s_red[2][0] + s_red[3][0];
    double fpD  = s_red[0][1] + s_red[1][1] + s_red[2][1] + s_red[3][1];
    double maskSum = s_red[0][2] + s_red[1][2] + s_red[2][2] + s_red[3][2];
    if (tid == 0) o_sa[b] = (float)sumA;
    int firstPad = (int)(fpD + 0.5);
    double scale;
    if (is_tr[0] != 0) {
      scale = (sumA == 0.0) ? 0.0 : (maskSum - 1.0) / (sumA > 1e-8 ? sumA : 1e-8);
    } else {
      scale = 1.0;
    }

    // scaled + pad-masked a; cumsum -> S
    double a[8], r[8];
    double run = 0.0;
#pragma unroll
    for (int k = 0; k < 8; ++k) {
      int t = t0 + k;
      double av = wd[k] * scale;
      if (t > firstPad) av = 0.0;
      a[k] = av;
      run += av; r[k] = run;
    }
    {
      float4* wvv = (float4*)(wsc + (long)b * T_ + t0);
      wvv[0] = make_float4((float)a[0], (float)a[1], (float)a[2], (float)a[3]);
      wvv[1] = make_float4((float)a[4], (float)a[5], (float)a[6], (float)a[7]);
    }
    double sc = run;
#pragma unroll
    for (int off = 1; off < 64; off <<= 1) {
      double n = __shfl_up(sc, off, 64);
      if (lane >= off) sc += n;
    }
    if (lane == 63) s_tot2[wv] = sc;
    __syncthreads();
    double base = 0.0;
    for (int i = 0; i < wv; ++i) base += s_tot2[i];
    double e = base + (sc - run);

    // prefix-min of Kp - t
    double m[8];
    double mn = 1e300;
#pragma unroll
    for (int k = 0; k < 8; ++k) {
      double S = e + r[k];
      double kp = ceil(S - 1.0); if (kp < 0.0) kp = 0.0;
      double D = kp - (double)(t0 + k);
      mn = fmin(mn, D);
      m[k] = mn;
    }
    double scm = mn;
#pragma unroll
    for (int off = 1; off < 64; off <<= 1) {
      double n = __shfl_up(scm, off, 64);
      if (lane >= off) scm = fmin(scm, n);
    }
    double exw = __shfl_up(scm, 1, 64);
    if (lane == 0) exw = 1e300;
    if (lane == 63) s_mtot[wv] = scm;
    __syncthreads();
    double mbase = 1e300;
    for (int i = 0; i < wv; ++i) mbase = fmin(mbase, s_mtot[i]);
    double Mexcl = fmin(mbase, exw);

    // fires
    float flags[8];
    int Cp = (t0 - 1) + (int)fmin(1.0, Mexcl);
#pragma unroll
    for (int k = 0; k < 8; ++k) {
      int t = t0 + k;
      double Mk = fmin(Mexcl, m[k]);
      int C = t + (int)fmin(1.0, Mk);
      bool fired = C > Cp;
      flags[k] = fired ? 1.0f : 0.0f;
      if (fired) fireT[(long)b * T_ + (C - 1)] = t;
      if (t == firstPad) s_int[0] = C;
      Cp = C;
    }
    {
      float4* fv = (float4*)(o_ff + (long)b * T_ + t0);
      fv[0] = make_float4(flags[0], flags[1], flags[2], flags[3]);
      fv[1] = make_float4(flags[4], flags[5], flags[6], flags[7]);
    }
    if (tid == 255) s_int[1] = Cp;
    __syncthreads();
    if (tid == 0) {
      int nA = s_int[1];
      nAllArr[b] = nA;
      nUnmArr[b] = (firstPad >= T_) ? nA : s_int[0];
    }
  }
  grid.sync();

  // ---------------- P3: all cif rows, grid-stride over (b,pos) ------------
  {
    int lane = tid & 63;
    int waveId = blockIdx.x * 4 + (tid >> 6);
    const int nWaves = 512 * 4;
    for (int task = waveId; task < B_ * L_; task += nWaves) {
      int b = task / L_;
      int pos = task - b * L_;
      int nA = nAllArr[b], nU = nUnmArr[b];
      float* crow = o_cif + ((long)b * L_ + pos) * H_ + lane * 4;
      if (pos > nU) {
        nt_store4(make_float4(0.0f, 0.0f, 0.0f, 0.0f), crow);
        if (lane == 0) o_np[(long)b * L_ + pos] = 0.0f;
        continue;
      }
      const int* ftb = fireT + (long)b * T_;
      int hi, anchor, lo;
      if (pos < nU) {
        hi = ftb[pos];
        anchor = (pos == 0) ? 0 : ftb[pos - 1];
        lo = (pos == 0) ? 0 : anchor + 1;
      } else {
        hi = T_ - 1;                       // final carry state fin_s
        anchor = (nA == 0) ? 0 : ftb[nA - 1];
        lo = (nA == 0) ? 0 : anchor + 1;
      }
      const float* xb = x + (long)b * T_ * H_;
      float4 acc = ((const float4*)(xb + (long)anchor * H_))[lane];
      float4 acc2 = make_float4(0.0f, 0.0f, 0.0f, 0.0f);
      const float* wb = wsc + (long)b * T_;
      int u = lo;
      for (; u + 1 <= hi; u += 2) {
        float f0 = 1.0f - wb[u];
        float f1 = 1.0f - wb[u + 1];
        float4 xv0 = ((const float4*)(xb + (long)u * H_))[lane];
        float4 xv1 = ((const float4*)(xb + (long)(u + 1) * H_))[lane];
        acc.x += f0 * xv0.x;  acc.y += f0 * xv0.y;
        acc.z += f0 * xv0.z;  acc.w += f0 * xv0.w;
        acc2.x += f1 * xv1.x; acc2.y += f1 * xv1.y;
        acc2.z += f1 * xv1.z; acc2.w += f1 * xv1.w;
      }
      if (u <= hi) {
        float f = 1.0f - wb[u];
        float4 xv = ((const float4*)(xb + (long)u * H_))[lane];
        acc.x += f * xv.x; acc.y += f * xv.y; acc.z += f * xv.z; acc.w += f * xv.w;
      }
      acc.x += acc2.x; acc.y += acc2.y; acc.z += acc2.z; acc.w += acc2.w;
      float ss = acc.x * acc.x + acc.y * acc.y + acc.z * acc.z + acc.w * acc.w;
#pragma unroll
      for (int off = 32; off > 0; off >>= 1) ss += __shfl_xor(ss, off, 64);
      float inv = 1.0f / fmaxf(sqrtf(ss), 1e-12f);
      nt_store4(make_float4(acc.x * inv, acc.y * inv, acc.z * inv, acc.w * inv), crow);
      if (lane == 0) o_np[(long)b * L_ + pos] = 1.0f;
    }
  }
}

// ---------------- launch ----------------
extern "C" void kernel_launch(void* const* d_in, const int* in_sizes, int n_in,
                              void* d_out, int out_size, void* d_ws, size_t ws_size,
                              hipStream_t stream) {
  const float* x    = (const float*)d_in[0];
  const float* mask = (const float*)d_in[1];
  const float* W1   = (const float*)d_in[2];
  const float* b1   = (const float*)d_in[3];
  const float* W2   = (const float*)d_in[4];
  const float* b2   = (const float*)d_in[5];
  const int*   istr = (const int*)d_in[6];

  float* out = (float*)d_out;
  // output layout (all fp32, concatenated in return order)
  float* o_cif = out;                                  // B*L*H
  float* o_ori = o_cif + (size_t)B_ * L_ * H_;         // B*T
  float* o_ff  = o_ori + (size_t)B_ * T_;              // B*T
  float* o_np  = o_ff  + (size_t)B_ * T_;              // B*L
  float* o_sa  = o_np  + (size_t)B_ * L_;              // B

  // workspace layout
  char* w = (char*)d_ws;
  double* vd   = (double*)w; w += 512 * 8;
  double* c0   = (double*)w; w += 8;
  double* d1   = (double*)w; w += (size_t)B_ * T_ * 8;
  double* d2   = (double*)w; w += (size_t)B_ * T_ * 8;
  float* absS  = (float*)w;  w += (size_t)B_ * T_ * 4;
  float* wsc   = (float*)w;  w += (size_t)B_ * T_ * 4;
  int* fireT   = (int*)w;    w += (size_t)B_ * T_ * 4;
  int* nAllA   = (int*)w;    w += B_ * 4;
  int* nUnmA   = (int*)w;    w += B_ * 4;

  void* args[] = {
    (void*)&x, (void*)&mask, (void*)&W1, (void*)&b1, (void*)&W2, (void*)&b2,
    (void*)&istr, (void*)&vd, (void*)&c0, (void*)&d1, (void*)&d2, (void*)&absS,
    (void*)&wsc, (void*)&fireT, (void*)&nAllA, (void*)&nUnmA,
    (void*)&o_cif, (void*)&o_ori, (void*)&o_ff, (void*)&o_np, (void*)&o_sa
  };
  hipLaunchCooperativeKernel(cif_fused, dim3(512), dim3(256), args, 0, stream);
}

// Round 9
// 154.253 us; speedup vs baseline: 2.5221x; 2.5221x over previous
//
#include <hip/hip_runtime.h>

#define B_ 32
#define T_ 2048
#define H_ 256
#define L_ 2049   // T_ + 1

// ---------------- helpers ----------------
__device__ inline double waveReduceD(double v) {
#pragma unroll
  for (int off = 32; off > 0; off >>= 1) v += __shfl_xor(v, off, 64);
  return v;
}

typedef float vfloat4 __attribute__((ext_vector_type(4)));
__device__ inline void nt_store4(float4 v, float* p) {
  vfloat4 t;
  t.x = v.x; t.y = v.y; t.z = v.z; t.w = v.w;
  __builtin_nontemporal_store(t, (vfloat4*)p);
}

// ---------------- K0: fold the two linear layers ----------------
// v[c] = sum_o W2[o] * W1[o,c]  (c in [0,512)),  c0 = W2.b1 + b2
__global__ void __launch_bounds__(256) k0_fold(
    const float* __restrict__ W1, const float* __restrict__ b1,
    const float* __restrict__ W2, const float* __restrict__ b2,
    double* __restrict__ vd, double* __restrict__ c0) {
  __shared__ double s_p[8][32];
  int tid = threadIdx.x;
  int cl = tid & 31, sl = tid >> 5;
  int c = blockIdx.x * 32 + cl;
  double acc0 = 0.0, acc1 = 0.0;   // dual acc: half the serial fp64 chain
#pragma unroll 4
  for (int o = sl * 64; o < sl * 64 + 64; o += 2) {
    acc0 += (double)W2[o] * (double)W1[o * 512 + c];
    acc1 += (double)W2[o + 1] * (double)W1[(o + 1) * 512 + c];
  }
  s_p[sl][cl] = acc0 + acc1;
  __syncthreads();
  if (sl == 0) {
    double v = 0.0;
#pragma unroll
    for (int i = 0; i < 8; ++i) v += s_p[i][cl];
    vd[c] = v;
  }
  if (blockIdx.x == 0) {
    __shared__ double red[256];
    double p = (double)W2[tid] * (double)b1[tid] +
               (double)W2[tid + 256] * (double)b1[tid + 256];
    red[tid] = p;
    __syncthreads();
    for (int s = 128; s > 0; s >>= 1) {
      if (tid < s) red[tid] += red[tid + s];
      __syncthreads();
    }
    if (tid == 0) c0[0] = red[0] + (double)b2[0];
  }
}

// ---------------- K1: row dots, 16 lanes per row ----------------
__global__ void __launch_bounds__(256) k1_rowdots(
    const float* __restrict__ x, const double* __restrict__ vd,
    double* __restrict__ d1, double* __restrict__ d2, float* __restrict__ absS) {
  int tid = threadIdx.x;
  int s = tid & 15;          // segment within row
  int slot = tid >> 4;       // 16 row-slots x 4 rows = 64 rows per block
  long rowBase = (long)blockIdx.x * 64;

  double v12[16], v2v[16];   // my 16-element slice of v2 and (v1+v2)
#pragma unroll
  for (int k = 0; k < 16; ++k) {
    double bv = vd[256 + s * 16 + k];
    v2v[k] = bv;
    v12[k] = vd[s * 16 + k] + bv;
  }

#pragma unroll
  for (int i = 0; i < 4; ++i) {
    long row = rowBase + slot * 4 + i;
    const float4* xr = (const float4*)(x + row * H_ + s * 16);
    float4 a0 = xr[0], a1 = xr[1], a2 = xr[2], a3 = xr[3];
    float e[16];
    *(float4*)(e + 0) = a0; *(float4*)(e + 4) = a1;
    *(float4*)(e + 8) = a2; *(float4*)(e + 12) = a3;
    double p1 = 0.0, p2 = 0.0;
    bool nz = false;
#pragma unroll
    for (int k = 0; k < 16; ++k) {
      p1 += (double)e[k] * v12[k];
      p2 += (double)e[k] * v2v[k];
      nz |= (e[k] != 0.0f);
    }
    float nzf = nz ? 1.0f : 0.0f;
#pragma unroll
    for (int off = 1; off < 16; off <<= 1) {  // stays inside the 16-group
      p1 += __shfl_xor(p1, off, 64);
      p2 += __shfl_xor(p2, off, 64);
      nzf += __shfl_xor(nzf, off, 64);
    }
    if (s == 0) {
      d1[row] = p1;
      d2[row] = p2;
      absS[row] = (nzf > 0.0f) ? 1.0f : 0.0f;
    }
  }
}

// ---------------- K24: weights+fire (redundant per block) + cif rows -----
// grid (32 pos-groups, 32 b). Every block recomputes its b's weight/fire
// solve (Part A + scans, ~2-3 us, d1/d2 are L3-hot) into LDS, then handles
// positions pos = pg + 32*idx (interleaved -> the ~200 work rows per b are
// spread over all 32 pgs). Fire closed form (exact for any a_t >= 0):
//   C_t = t + min(1, M_t),  M_t = min_{s<=t}(Kp_s - s),
//   Kp_t = max(0, ceil(S_t - 1)),  S = cumsum(a).
// pg==0 additionally writes o_ori / o_ff / o_sa.
__global__ void __launch_bounds__(256) k24_rows(
    const float* __restrict__ x, const float* __restrict__ mask,
    const int* __restrict__ is_tr, const double* __restrict__ c0p,
    const double* __restrict__ d1, const double* __restrict__ d2,
    const float* __restrict__ absS,
    float* __restrict__ o_cif, float* __restrict__ o_ori,
    float* __restrict__ o_ff, float* __restrict__ o_np,
    float* __restrict__ o_sa) {
  __shared__ double s_P[T_];        // 16 KB prefix sums of d2
  __shared__ float s_wf[T_];        // 8 KB scaled+masked w
  __shared__ int s_fireT[T_];       // 8 KB fire times by rank
  __shared__ double s_tot[4];
  __shared__ double s_red[4][3];
  __shared__ double s_tot2[4];
  __shared__ double s_mtot[4];
  __shared__ int s_int[2];          // [0]=C@firstPad, [1]=nA
  int pg = blockIdx.x, b = blockIdx.y;
  int tid = threadIdx.x;
  int lane = tid & 63, wv = tid >> 6;
  int t0 = tid * 8;
  const double* d1b = d1 + (long)b * T_;
  const double* d2b = d2 + (long)b * T_;
  const float* asb = absS + (long)b * T_;
  double c0 = c0p[0];

  // ---- prefix sum of d2 -> s_P ----
  double r2[8];
  {
    double run2 = 0.0;
#pragma unroll
    for (int k = 0; k < 8; ++k) { run2 += d2b[t0 + k]; r2[k] = run2; }
    double sc2 = run2;
#pragma unroll
    for (int off = 1; off < 64; off <<= 1) {
      double n = __shfl_up(sc2, off, 64);
      if (lane >= off) sc2 += n;
    }
    if (lane == 63) s_tot[wv] = sc2;
    __syncthreads();
    double base2 = 0.0;
    for (int i = 0; i < wv; ++i) base2 += s_tot[i];
    double e2 = base2 + (sc2 - run2);
#pragma unroll
    for (int k = 0; k < 8; ++k) s_P[t0 + k] = e2 + r2[k];
  }
  __syncthreads();

  // ---- Part A: w = clip(relu(d1 - windowmean + c0), 0, 1) ----
  double wd[8];
  double sa = 0.0, fpc = 0.0;
#pragma unroll
  for (int k = 0; k < 8; ++k) {
    int t = t0 + k;
    double wvv;
    if (t == 0) {
      wvv = d1b[0] - s_P[0] + c0;  // hist[0] = x[0]
    } else {
      int start = t - 10; if (start < 0) start = 0;
      double ws_ = s_P[t - 1] - (start > 0 ? s_P[start - 1] : 0.0);
      wvv = d1b[t] - ws_ / (double)(t - start) + c0;
    }
    wvv = wvv < 0.0 ? 0.0 : (wvv > 1.0 ? 1.0 : wvv);
    wd[k] = wvv;
    sa += wvv;
    fpc += (asb[t] != 0.0f) ? 1.0 : 0.0;
  }
  if (pg == 0) {
    float4* ov = (float4*)(o_ori + (long)b * T_ + t0);
    ov[0] = make_float4((float)wd[0], (float)wd[1], (float)wd[2], (float)wd[3]);
    ov[1] = make_float4((float)wd[4], (float)wd[5], (float)wd[6], (float)wd[7]);
  }
  // ---- reductions (sumA, firstPad count, maskSum) ----
  double ms = (tid < 200) ? (double)mask[(long)b * 200 + tid] : 0.0;
  double sar = waveReduceD(sa), fpr = waveReduceD(fpc), msr = waveReduceD(ms);
  if (lane == 0) { s_red[wv][0] = sar; s_red[wv][1] = fpr; s_red[wv][2] = msr; }
  __syncthreads();
  double sumA = s_red[0][0] + s_red[1][0] + s_red[2][0] + s_red[3][0];
  double fpD  = s_red[0][1] + s_red[1][1] + s_red[2][1] + s_red[3][1];
  double maskSum = s_red[0][2] + s_red[1][2] + s_red[2][2] + s_red[3][2];
  if (pg == 0 && tid == 0) o_sa[b] = (float)sumA;
  int firstPad = (int)(fpD + 0.5);
  double scale;
  if (is_tr[0] != 0) {
    scale = (sumA == 0.0) ? 0.0 : (maskSum - 1.0) / (sumA > 1e-8 ? sumA : 1e-8);
  } else {
    scale = 1.0;
  }

  // ---- scaled + pad-masked a -> s_wf; cumsum -> S ----
  double a[8], r[8];
  double run = 0.0;
#pragma unroll
  for (int k = 0; k < 8; ++k) {
    int t = t0 + k;
    double av = wd[k] * scale;
    if (t > firstPad) av = 0.0;
    a[k] = av;
    run += av; r[k] = run;
    s_wf[t] = (float)av;
  }
  double sc = run;
#pragma unroll
  for (int off = 1; off < 64; off <<= 1) {
    double n = __shfl_up(sc, off, 64);
    if (lane >= off) sc += n;
  }
  if (lane == 63) s_tot2[wv] = sc;
  __syncthreads();
  double base = 0.0;
  for (int i = 0; i < wv; ++i) base += s_tot2[i];
  double e = base + (sc - run);  // exclusive prefix for this thread

  // ---- prefix-min of Kp - t ----
  double m[8];
  double mn = 1e300;
#pragma unroll
  for (int k = 0; k < 8; ++k) {
    double S = e + r[k];
    double kp = ceil(S - 1.0); if (kp < 0.0) kp = 0.0;
    double D = kp - (double)(t0 + k);
    mn = fmin(mn, D);
    m[k] = mn;
  }
  double scm = mn;
#pragma unroll
  for (int off = 1; off < 64; off <<= 1) {
    double n = __shfl_up(scm, off, 64);
    if (lane >= off) scm = fmin(scm, n);
  }
  double exw = __shfl_up(scm, 1, 64);       // wave-exclusive inclusive-min
  if (lane == 0) exw = 1e300;
  if (lane == 63) s_mtot[wv] = scm;
  __syncthreads();
  double mbase = 1e300;
  for (int i = 0; i < wv; ++i) mbase = fmin(mbase, s_mtot[i]);
  double Mexcl = fmin(mbase, exw);          // min over s < t0

  // ---- fires -> s_fireT (LDS) ----
  float flags[8];
  int Cp = (t0 - 1) + (int)fmin(1.0, Mexcl);  // t0==0: Mexcl=inf -> C_{-1}=0
#pragma unroll
  for (int k = 0; k < 8; ++k) {
    int t = t0 + k;
    double Mk = fmin(Mexcl, m[k]);
    int C = t + (int)fmin(1.0, Mk);
    bool fired = C > Cp;
    flags[k] = fired ? 1.0f : 0.0f;
    if (fired) s_fireT[C - 1] = t;
    if (t == firstPad) s_int[0] = C;
    Cp = C;
  }
  if (pg == 0) {
    float4* fv = (float4*)(o_ff + (long)b * T_ + t0);
    fv[0] = make_float4(flags[0], flags[1], flags[2], flags[3]);
    fv[1] = make_float4(flags[4], flags[5], flags[6], flags[7]);
  }
  if (tid == 255) s_int[1] = Cp;  // nA = C_{T-1}
  __syncthreads();
  int nA = s_int[1];
  int nU = (firstPad >= T_) ? nA : s_int[0];

  // ---- Phase B: cif rows pos = pg + 32*idx (interleaved load balance) ----
  int wave = wv;
  const float* xb = x + (long)b * T_ * H_;
  for (int idx = wave; pg + 32 * idx < L_; idx += 4) {
    int pos = pg + 32 * idx;
    float* crow = o_cif + ((long)b * L_ + pos) * H_ + lane * 4;
    if (pos > nU) {
      nt_store4(make_float4(0.0f, 0.0f, 0.0f, 0.0f), crow);
      if (lane == 0) o_np[(long)b * L_ + pos] = 0.0f;
      continue;
    }
    int hi, anchor, lo;
    if (pos < nU) {
      hi = s_fireT[pos];
      anchor = (pos == 0) ? 0 : s_fireT[pos - 1];
      lo = (pos == 0) ? 0 : anchor + 1;
    } else {
      hi = T_ - 1;                       // final carry state fin_s
      anchor = (nA == 0) ? 0 : s_fireT[nA - 1];
      lo = (nA == 0) ? 0 : anchor + 1;
    }
    float4 acc = ((const float4*)(xb + (long)anchor * H_))[lane];
    float4 acc2 = make_float4(0.0f, 0.0f, 0.0f, 0.0f);
    int u = lo;
    for (; u + 1 <= hi; u += 2) {   // dual accumulators
      float f0 = 1.0f - s_wf[u];
      float f1 = 1.0f - s_wf[u + 1];
      float4 xv0 = ((const float4*)(xb + (long)u * H_))[lane];
      float4 xv1 = ((const float4*)(xb + (long)(u + 1) * H_))[lane];
      acc.x += f0 * xv0.x;  acc.y += f0 * xv0.y;
      acc.z += f0 * xv0.z;  acc.w += f0 * xv0.w;
      acc2.x += f1 * xv1.x; acc2.y += f1 * xv1.y;
      acc2.z += f1 * xv1.z; acc2.w += f1 * xv1.w;
    }
    if (u <= hi) {
      float f = 1.0f - s_wf[u];
      float4 xv = ((const float4*)(xb + (long)u * H_))[lane];
      acc.x += f * xv.x; acc.y += f * xv.y; acc.z += f * xv.z; acc.w += f * xv.w;
    }
    acc.x += acc2.x; acc.y += acc2.y; acc.z += acc2.z; acc.w += acc2.w;
    float ss = acc.x * acc.x + acc.y * acc.y + acc.z * acc.z + acc.w * acc.w;
#pragma unroll
    for (int off = 32; off > 0; off >>= 1) ss += __shfl_xor(ss, off, 64);
    float inv = 1.0f / fmaxf(sqrtf(ss), 1e-12f);
    nt_store4(make_float4(acc.x * inv, acc.y * inv, acc.z * inv, acc.w * inv), crow);
    if (lane == 0) o_np[(long)b * L_ + pos] = 1.0f;
  }
}

// ---------------- launch ----------------
extern "C" void kernel_launch(void* const* d_in, const int* in_sizes, int n_in,
                              void* d_out, int out_size, void* d_ws, size_t ws_size,
                              hipStream_t stream) {
  const float* x    = (const float*)d_in[0];
  const float* mask = (const float*)d_in[1];
  const float* W1   = (const float*)d_in[2];
  const float* b1   = (const float*)d_in[3];
  const float* W2   = (const float*)d_in[4];
  const float* b2   = (const float*)d_in[5];
  const int*   istr = (const int*)d_in[6];

  float* out = (float*)d_out;
  // output layout (all fp32, concatenated in return order)
  float* o_cif = out;                                  // B*L*H
  float* o_ori = o_cif + (size_t)B_ * L_ * H_;         // B*T
  float* o_ff  = o_ori + (size_t)B_ * T_;              // B*T
  float* o_np  = o_ff  + (size_t)B_ * T_;              // B*L
  float* o_sa  = o_np  + (size_t)B_ * L_;              // B

  // workspace layout
  char* w = (char*)d_ws;
  double* vd   = (double*)w; w += 512 * 8;
  double* c0   = (double*)w; w += 8;
  double* d1   = (double*)w; w += (size_t)B_ * T_ * 8;
  double* d2   = (double*)w; w += (size_t)B_ * T_ * 8;
  float* absS  = (float*)w;  w += (size_t)B_ * T_ * 4;

  // k0 -> k1 -> k24 (k2 merged into k24; its outputs live in LDS per block)
  k0_fold<<<16, 256, 0, stream>>>(W1, b1, W2, b2, vd, c0);
  k1_rowdots<<<(B_ * T_) / 64, 256, 0, stream>>>(x, vd, d1, d2, absS);
  k24_rows<<<dim3(32, B_), 256, 0, stream>>>(x, mask, istr, c0, d1, d2, absS,
                                             o_cif, o_ori, o_ff, o_np, o_sa);
}